// Round 1
// baseline (1120.655 us; speedup 1.0000x reference)
//
#include <hip/hip_runtime.h>

#define NPTS 262144
#define TILE_R 256
#define NTH 512

__global__ __launch_bounds__(NTH, 1)
void fused_onescale(const float* __restrict__ x, const int* __restrict__ bin,
                    const int* __restrict__ sel, int M,
                    const float* __restrict__ Wd1, const float* __restrict__ bd1, const float* __restrict__ ad,
                    const float* __restrict__ Wd2, const float* __restrict__ bd2,
                    const float* __restrict__ Wp1, const float* __restrict__ bp1, const float* __restrict__ ap,
                    const float* __restrict__ Wp2, const float* __restrict__ bp2,
                    const float* __restrict__ Wu1, const float* __restrict__ bu1, const float* __restrict__ au1,
                    const float* __restrict__ Wu2, const float* __restrict__ bu2, const float* __restrict__ au2,
                    const float* __restrict__ Wu3, const float* __restrict__ bu3,
                    const float* __restrict__ Wu4, const float* __restrict__ bu4,
                    float* __restrict__ outF, float* __restrict__ outP, float* __restrict__ outO)
{
    // LDS: 159,744 bytes total (<= 160 KiB)
    __shared__ __align__(16) float A[64][TILE_R];     // activation buffer 1 (xT: [chan][row])
    __shared__ __align__(16) float Bb[64][TILE_R];    // activation buffer 2
    __shared__ __align__(16) float Wl[64][64];        // staged weight tile [k][col]
    __shared__ __align__(16) float Wx[8][64];         // W_u1 rows 64..71 (bit channels)
    __shared__ __align__(16) float bitsF[8][TILE_R];  // bit planes (256.0 / 0.0), xT layout
    __shared__ int   baseI[TILE_R];
    __shared__ int   maskI[TILE_R];

    const int tid = threadIdx.x;
    const int n0  = blockIdx.x * TILE_R;
    const int tr  = tid >> 4;          // 0..31
    const int tc  = tid & 15;          // 0..15
    const int r0  = tr * 8;            // 8 rows / thread
    const int c0  = tc * 4;            // 4 cols / thread

    float acc[8][4];

    auto stageW = [&](const float* G, int gcols, int cc, int w) {
#pragma unroll
        for (int t = 0; t < 8; ++t) {
            int idx = t * NTH + tid;
            int k = idx >> 6, c = idx & 63;
            Wl[k][c] = (c < w) ? G[k * gcols + cc + c] : 0.f;
        }
    };

    auto gemm = [&](const float (*S)[TILE_R]) {
#pragma unroll
        for (int i = 0; i < 8; ++i)
#pragma unroll
            for (int j = 0; j < 4; ++j) acc[i][j] = 0.f;
#pragma unroll 4
        for (int k = 0; k < 64; ++k) {
            float4 a0 = *(const float4*)&S[k][r0];
            float4 a1 = *(const float4*)&S[k][r0 + 4];
            float4 b  = *(const float4*)&Wl[k][c0];
            float av[8] = {a0.x, a0.y, a0.z, a0.w, a1.x, a1.y, a1.z, a1.w};
            float bv[4] = {b.x, b.y, b.z, b.w};
#pragma unroll
            for (int i = 0; i < 8; ++i)
#pragma unroll
                for (int j = 0; j < 4; ++j)
                    acc[i][j] = fmaf(av[i], bv[j], acc[i][j]);
        }
    };

    auto writeT = [&](float (*D)[TILE_R], const float (*t)[4]) {
#pragma unroll
        for (int j = 0; j < 4; ++j) {
            *(float4*)&D[c0 + j][r0]     = make_float4(t[0][j], t[1][j], t[2][j], t[3][j]);
            *(float4*)&D[c0 + j][r0 + 4] = make_float4(t[4][j], t[5][j], t[6][j], t[7][j]);
        }
    };

    // ---------------- P0: stage x (transposed) + bit bookkeeping ----------------
#pragma unroll
    for (int t = 0; t < 8; ++t) {
        int row = (tid >> 4) + 32 * t;
        int cc4 = (tid & 15) * 4;
        float4 v = *(const float4*)&x[(size_t)(n0 + row) * 64 + cc4];
        A[cc4 + 0][row] = v.x; A[cc4 + 1][row] = v.y;
        A[cc4 + 2][row] = v.z; A[cc4 + 3][row] = v.w;
    }
    if (tid < TILE_R) {
        int r = tid, n = n0 + r;
        int m = 0;
#pragma unroll
        for (int j = 0; j < 8; ++j) m |= (bin[n * 8 + j] & 1) << j;
        maskI[r] = m;
        outO[n] = (float)(m - 1);            // sum(bin<<j) == mask value
#pragma unroll
        for (int j = 0; j < 8; ++j) bitsF[j][r] = ((m >> j) & 1) ? 256.f : 0.f;
        int lo = 0, hi = M, tgt = n * 8;     // lower_bound(sel, 8n)
        while (lo < hi) { int mid = (lo + hi) >> 1; if (sel[mid] < tgt) lo = mid + 1; else hi = mid; }
        baseI[r] = lo;
    }

    // ---------------- P1: h = prelu(x@Wd1 + bd1) -> Bb ----------------
    __syncthreads();
    stageW(Wd1, 64, 0, 64);
    __syncthreads();
    gemm(A);
    {
        float4 bb = *(const float4*)&bd1[c0];
        float4 aa = *(const float4*)&ad[c0];
        float bv[4] = {bb.x, bb.y, bb.z, bb.w}, av[4] = {aa.x, aa.y, aa.z, aa.w};
        float t[8][4];
#pragma unroll
        for (int i = 0; i < 8; ++i)
#pragma unroll
            for (int j = 0; j < 4; ++j) {
                float v = acc[i][j] + bv[j];
                t[i][j] = v >= 0.f ? v : av[j] * v;
            }
        writeT(Bb, t);
    }

    // ---------------- P2: rec = x + h@Wd2 + bd2 -> A (in place) ----------------
    __syncthreads();
    stageW(Wd2, 64, 0, 64);
    __syncthreads();
    gemm(Bb);
    {
        float4 bb = *(const float4*)&bd2[c0];
        float bv[4] = {bb.x, bb.y, bb.z, bb.w};
#pragma unroll
        for (int j = 0; j < 4; ++j) {
            float4 o0 = *(float4*)&A[c0 + j][r0];
            float4 o1 = *(float4*)&A[c0 + j][r0 + 4];
            o0.x += acc[0][j] + bv[j]; o0.y += acc[1][j] + bv[j];
            o0.z += acc[2][j] + bv[j]; o0.w += acc[3][j] + bv[j];
            o1.x += acc[4][j] + bv[j]; o1.y += acc[5][j] + bv[j];
            o1.z += acc[6][j] + bv[j]; o1.w += acc[7][j] + bv[j];
            *(float4*)&A[c0 + j][r0]     = o0;
            *(float4*)&A[c0 + j][r0 + 4] = o1;
        }
    }

    // ---------------- P3: p = prelu(rec@Wp1 + bp1) -> Bb ----------------
    __syncthreads();
    stageW(Wp1, 64, 0, 64);
    __syncthreads();
    gemm(A);
    {
        float4 bb = *(const float4*)&bp1[c0];
        float4 aa = *(const float4*)&ap[c0];
        float bv[4] = {bb.x, bb.y, bb.z, bb.w}, av[4] = {aa.x, aa.y, aa.z, aa.w};
        float t[8][4];
#pragma unroll
        for (int i = 0; i < 8; ++i)
#pragma unroll
            for (int j = 0; j < 4; ++j) {
                float v = acc[i][j] + bv[j];
                t[i][j] = v >= 0.f ? v : av[j] * v;
            }
        writeT(Bb, t);
    }

    // ---------------- P4: cur_pred = p@Wp2 + bp2 (4 chunks of <=64 cols) ----------------
    for (int cc = 0; cc < 255; cc += 64) {
        int w = (255 - cc) < 64 ? (255 - cc) : 64;
        __syncthreads();
        stageW(Wp2, 255, cc, w);
        __syncthreads();
        gemm(Bb);
#pragma unroll
        for (int i = 0; i < 8; ++i) {
            size_t ro = (size_t)(n0 + r0 + i) * 255 + cc;
#pragma unroll
            for (int j = 0; j < 4; ++j) {
                int c = c0 + j;
                if (c < w) outP[ro + c] = acc[i][j] + bp2[cc + c];
            }
        }
    }

    // ---------------- P5: u = prelu([rec,bits]@Wu1 + bu1) -> Bb ----------------
    __syncthreads();
    stageW(Wu1, 64, 0, 64);
    { int k8 = tid >> 6, c = tid & 63; Wx[k8][c] = Wu1[(64 + k8) * 64 + c]; }
    __syncthreads();
    gemm(A);
#pragma unroll
    for (int k = 0; k < 8; ++k) {   // K-tail: 8 bit channels
        float4 a0 = *(const float4*)&bitsF[k][r0];
        float4 a1 = *(const float4*)&bitsF[k][r0 + 4];
        float4 b  = *(const float4*)&Wx[k][c0];
        float av[8] = {a0.x, a0.y, a0.z, a0.w, a1.x, a1.y, a1.z, a1.w};
        float bv[4] = {b.x, b.y, b.z, b.w};
#pragma unroll
        for (int i = 0; i < 8; ++i)
#pragma unroll
            for (int j = 0; j < 4; ++j)
                acc[i][j] = fmaf(av[i], bv[j], acc[i][j]);
    }
    {
        float4 bb = *(const float4*)&bu1[c0];
        float4 aa = *(const float4*)&au1[c0];
        float bv[4] = {bb.x, bb.y, bb.z, bb.w}, av[4] = {aa.x, aa.y, aa.z, aa.w};
        float t[8][4];
#pragma unroll
        for (int i = 0; i < 8; ++i)
#pragma unroll
            for (int j = 0; j < 4; ++j) {
                float v = acc[i][j] + bv[j];
                t[i][j] = v >= 0.f ? v : av[j] * v;
            }
        writeT(Bb, t);
    }

    // ---------------- P6: h2 = prelu(u@Wu2 + bu2) -> A ----------------
    __syncthreads();
    stageW(Wu2, 64, 0, 64);
    __syncthreads();
    gemm(Bb);
    {
        float4 bb = *(const float4*)&bu2[c0];
        float4 aa = *(const float4*)&au2[c0];
        float bv[4] = {bb.x, bb.y, bb.z, bb.w}, av[4] = {aa.x, aa.y, aa.z, aa.w};
        float t[8][4];
#pragma unroll
        for (int i = 0; i < 8; ++i)
#pragma unroll
            for (int j = 0; j < 4; ++j) {
                float v = acc[i][j] + bv[j];
                t[i][j] = v >= 0.f ? v : av[j] * v;
            }
        writeT(A, t);
    }

    // ---------------- P7: u = u + h2@Wu3 + bu3 -> Bb (in place) ----------------
    __syncthreads();
    stageW(Wu3, 64, 0, 64);
    __syncthreads();
    gemm(A);
    {
        float4 bb = *(const float4*)&bu3[c0];
        float bv[4] = {bb.x, bb.y, bb.z, bb.w};
#pragma unroll
        for (int j = 0; j < 4; ++j) {
            float4 o0 = *(float4*)&Bb[c0 + j][r0];
            float4 o1 = *(float4*)&Bb[c0 + j][r0 + 4];
            o0.x += acc[0][j] + bv[j]; o0.y += acc[1][j] + bv[j];
            o0.z += acc[2][j] + bv[j]; o0.w += acc[3][j] + bv[j];
            o1.x += acc[4][j] + bv[j]; o1.y += acc[5][j] + bv[j];
            o1.z += acc[6][j] + bv[j]; o1.w += acc[7][j] + bv[j];
            *(float4*)&Bb[c0 + j][r0]     = o0;
            *(float4*)&Bb[c0 + j][r0 + 4] = o1;
        }
    }

    // ---------------- P8: up = u@Wu4 + bu4, masked scatter (8 chunks == 8 children) ----------------
    for (int ch = 0; ch < 8; ++ch) {
        __syncthreads();
        stageW(Wu4, 512, ch * 64, 64);
        __syncthreads();
        gemm(Bb);
        float4 bb = *(const float4*)&bu4[ch * 64 + c0];
#pragma unroll
        for (int i = 0; i < 8; ++i) {
            int r = r0 + i;
            int mk = maskI[r];
            if ((mk >> ch) & 1) {
                int d = baseI[r] + __popc(mk & ((1 << ch) - 1));
                float4 v;
                v.x = acc[i][0] + bb.x; v.y = acc[i][1] + bb.y;
                v.z = acc[i][2] + bb.z; v.w = acc[i][3] + bb.w;
                *(float4*)&outF[(size_t)d * 64 + c0] = v;
            }
        }
    }
}

extern "C" void kernel_launch(void* const* d_in, const int* in_sizes, int n_in,
                              void* d_out, int out_size, void* d_ws, size_t ws_size,
                              hipStream_t stream) {
    const float* x   = (const float*)d_in[0];
    const int*   bin = (const int*)d_in[1];
    const int*   sel = (const int*)d_in[2];
    const int    M   = in_sizes[2];
    const float *Wd1 = (const float*)d_in[3],  *bd1 = (const float*)d_in[4],  *ad  = (const float*)d_in[5];
    const float *Wd2 = (const float*)d_in[6],  *bd2 = (const float*)d_in[7];
    const float *Wp1 = (const float*)d_in[8],  *bp1 = (const float*)d_in[9],  *ap  = (const float*)d_in[10];
    const float *Wp2 = (const float*)d_in[11], *bp2 = (const float*)d_in[12];
    const float *Wu1 = (const float*)d_in[13], *bu1 = (const float*)d_in[14], *au1 = (const float*)d_in[15];
    const float *Wu2 = (const float*)d_in[16], *bu2 = (const float*)d_in[17], *au2 = (const float*)d_in[18];
    const float *Wu3 = (const float*)d_in[19], *bu3 = (const float*)d_in[20];
    const float *Wu4 = (const float*)d_in[21], *bu4 = (const float*)d_in[22];

    float* out  = (float*)d_out;
    float* outF = out;                              // [M, 64]
    float* outP = out + (size_t)M * 64;             // [N, 255]
    float* outO = outP + (size_t)NPTS * 255;        // [N]

    fused_onescale<<<NPTS / TILE_R, NTH, 0, stream>>>(
        x, bin, sel, M,
        Wd1, bd1, ad, Wd2, bd2, Wp1, bp1, ap, Wp2, bp2,
        Wu1, bu1, au1, Wu2, bu2, au2, Wu3, bu3, Wu4, bu4,
        outF, outP, outO);
}

// Round 2
// 734.800 us; speedup vs baseline: 1.5251x; 1.5251x over previous
//
#include <hip/hip_runtime.h>

#define NPTS 262144
#define TILE_R 128
#define NTH 512
#define NBLK (NPTS / TILE_R)

typedef __attribute__((ext_vector_type(8))) short short8;
typedef __attribute__((ext_vector_type(4))) short short4v;
typedef __attribute__((ext_vector_type(4))) float f32x4;
typedef __attribute__((ext_vector_type(4), aligned(4))) float f32x4u;

__device__ __forceinline__ short f2bf(float f) {
    unsigned u = __builtin_bit_cast(unsigned, f);
    u += 0x7FFFu + ((u >> 16) & 1u);
    return (short)(u >> 16);
}
__device__ __forceinline__ float bf2f(short h) {
    return __builtin_bit_cast(float, ((unsigned)(unsigned short)h) << 16);
}

// weight fragment offsets in short units (frag layout: [ct][kb][hi/lo][lane64][8])
#define OFF_D1 0
#define OFF_D2 8192
#define OFF_P1 16384
#define OFF_P2 24576
#define OFF_U1 57344
#define OFF_U2 69632
#define OFF_U3 77824
#define OFF_U4 86016
// short8-unit bases
#define B_D1 0
#define B_D2 1024
#define B_P1 2048
#define B_P2 3072
#define B_U1 7168
#define B_U2 8704
#define B_U3 9728
#define B_U4 10752

#define MFMA(a, b, c) __builtin_amdgcn_mfma_f32_16x16x32_bf16(a, b, c, 0, 0, 0)

__device__ __forceinline__ void prep_one(const float* __restrict__ W, int K, int C, int nkb,
                                         short* __restrict__ dst, int idx) {
    int fi = idx & 511;
    int blk = idx >> 9;
    int kb = blk % nkb, ct = blk / nkb;
    int l = fi >> 3, i = fi & 7;
    int k = kb * 32 + 8 * (l >> 4) + i;
    int c = ct * 16 + (l & 15);
    float w = (k < K && c < C) ? W[k * C + c] : 0.f;
    short hi = f2bf(w);
    short lo = f2bf(w - bf2f(hi));
    dst[((ct * nkb + kb) * 2 + 0) * 512 + fi] = hi;
    dst[((ct * nkb + kb) * 2 + 1) * 512 + fi] = lo;
}

__global__ void prep_weights(const float* Wd1, const float* Wd2, const float* Wp1, const float* Wp2,
                             const float* Wu1, const float* Wu2, const float* Wu3, const float* Wu4,
                             short* ws) {
    int b = blockIdx.x, t = threadIdx.x;
    if      (b < 16)  prep_one(Wd1, 64, 64, 2, ws + OFF_D1, (b - 0) * 256 + t);
    else if (b < 32)  prep_one(Wd2, 64, 64, 2, ws + OFF_D2, (b - 16) * 256 + t);
    else if (b < 48)  prep_one(Wp1, 64, 64, 2, ws + OFF_P1, (b - 32) * 256 + t);
    else if (b < 112) prep_one(Wp2, 64, 255, 2, ws + OFF_P2, (b - 48) * 256 + t);
    else if (b < 136) prep_one(Wu1, 72, 64, 3, ws + OFF_U1, (b - 112) * 256 + t);
    else if (b < 152) prep_one(Wu2, 64, 64, 2, ws + OFF_U2, (b - 136) * 256 + t);
    else if (b < 168) prep_one(Wu3, 64, 64, 2, ws + OFF_U3, (b - 152) * 256 + t);
    else              prep_one(Wu4, 64, 512, 2, ws + OFF_U4, (b - 168) * 256 + t);
}

__global__ __launch_bounds__(NTH, 4)
void fused_main(const float* __restrict__ x, const int* __restrict__ bin, const int* __restrict__ sel, int M,
                const float* __restrict__ bd1, const float* __restrict__ ad,
                const float* __restrict__ bd2,
                const float* __restrict__ bp1, const float* __restrict__ ap,
                const float* __restrict__ bp2,
                const float* __restrict__ bu1, const float* __restrict__ au1,
                const float* __restrict__ bu2, const float* __restrict__ au2,
                const float* __restrict__ bu3, const float* __restrict__ bu4,
                const short* __restrict__ wsS,
                float* __restrict__ outF, float* __restrict__ outP, float* __restrict__ outO)
{
    // act buffers in B-fragment order: [buf][hi/lo][stripe8][kb2][lane64][8 bf16] = 64KB
    __shared__ __align__(16) short Abuf[2][2][8][2][64][8];
    __shared__ int maskI[TILE_R];
    __shared__ int baseI[TILE_R];

    const int tid = threadIdx.x;
    const int wv = tid >> 6;       // wave id 0..7 == stripe owned
    const int l  = tid & 63;
    const int g  = l >> 4;         // k-group within fragment
    const int ln = l & 15;         // point-within-stripe (B) / channel-within-tile (A/D col)
    const int n0 = blockIdx.x * TILE_R;
    const int nloc  = wv * 16 + ln;
    const int nglob = n0 + nloc;

    const short8* F = (const short8*)wsS;

    auto afr = [&](int b, int h, int st, int kb) -> short8 {
        return *(const short8*)&Abuf[b][h][st][kb][l][0];
    };
    auto wf = [&](int base8, int nkb, int ct, int kb, int h) -> short8 {
        return F[base8 + ((ct * nkb + kb) * 2 + h) * 64 + l];
    };
    // write v (4 consecutive channels 16t+4g+0..3 of point nloc) into buf b as hi/lo frags
    auto awr = [&](int b, int t, f32x4 v) {
        short h0 = f2bf(v[0]), h1 = f2bf(v[1]), h2 = f2bf(v[2]), h3 = f2bf(v[3]);
        short m0 = f2bf(v[0] - bf2f(h0)), m1 = f2bf(v[1] - bf2f(h1));
        short m2 = f2bf(v[2] - bf2f(h2)), m3 = f2bf(v[3] - bf2f(h3));
        int lane2 = 16 * (2 * (t & 1) + (g >> 1)) + ln;
        int kb = t >> 1, i0 = 4 * (g & 1);
        short4v a; a[0] = h0; a[1] = h1; a[2] = h2; a[3] = h3;
        short4v c; c[0] = m0; c[1] = m1; c[2] = m2; c[3] = m3;
        *(short4v*)&Abuf[b][0][wv][kb][lane2][i0] = a;
        *(short4v*)&Abuf[b][1][wv][kb][lane2][i0] = c;
    };

#define GEMM6(base8, nkb, ct, AH0, AH1, AL0, AL1, ACC) do {                      \
        short8 wh0 = wf(base8, nkb, ct, 0, 0), wl0 = wf(base8, nkb, ct, 0, 1);   \
        short8 wh1 = wf(base8, nkb, ct, 1, 0), wl1 = wf(base8, nkb, ct, 1, 1);   \
        ACC = MFMA(wh0, AH0, ACC); ACC = MFMA(wh1, AH1, ACC);                    \
        ACC = MFMA(wh0, AL0, ACC); ACC = MFMA(wh1, AL1, ACC);                    \
        ACC = MFMA(wl0, AH0, ACC); ACC = MFMA(wl1, AH1, ACC);                    \
    } while (0)

    // ---------------- P0: stage x as hi/lo fragments + bookkeeping ----------------
#pragma unroll
    for (int q = 0; q < 4; ++q) {
        int f4 = tid + NTH * q;            // float4 id within tile
        int n  = f4 >> 4;                  // 0..127
        int k0 = (f4 & 15) * 4;
        f32x4 v = *(const f32x4*)&x[(size_t)(n0 + n) * 64 + k0];
        short h0 = f2bf(v[0]), h1 = f2bf(v[1]), h2 = f2bf(v[2]), h3 = f2bf(v[3]);
        short m0 = f2bf(v[0] - bf2f(h0)), m1 = f2bf(v[1] - bf2f(h1));
        short m2 = f2bf(v[2] - bf2f(h2)), m3 = f2bf(v[3] - bf2f(h3));
        int st = n >> 4;
        int lane2 = 16 * ((k0 & 31) >> 3) + (n & 15);
        int kb = k0 >> 5, i0 = k0 & 7;
        short4v a; a[0] = h0; a[1] = h1; a[2] = h2; a[3] = h3;
        short4v c; c[0] = m0; c[1] = m1; c[2] = m2; c[3] = m3;
        *(short4v*)&Abuf[0][0][st][kb][lane2][i0] = a;
        *(short4v*)&Abuf[0][1][st][kb][lane2][i0] = c;
    }
    if (tid < TILE_R) {
        int n = n0 + tid;
        int m = 0;
#pragma unroll
        for (int j = 0; j < 8; ++j) m |= (bin[n * 8 + j] & 1) << j;
        maskI[tid] = m;
        outO[n] = (float)(m - 1);
        int lo = 0, hi = M, tgt = n * 8;
        while (lo < hi) { int mid = (lo + hi) >> 1; if (sel[mid] < tgt) lo = mid + 1; else hi = mid; }
        baseI[tid] = lo;
    }
    __syncthreads();

    // ---------------- P1: h = prelu(x@Wd1+bd1) -> buf1 (wave-local) ----------------
    {
        short8 ah0 = afr(0, 0, wv, 0), ah1 = afr(0, 0, wv, 1);
        short8 al0 = afr(0, 1, wv, 0), al1 = afr(0, 1, wv, 1);
#pragma unroll
        for (int t = 0; t < 4; ++t) {
            f32x4 acc = {0.f, 0.f, 0.f, 0.f};
            GEMM6(B_D1, 2, t, ah0, ah1, al0, al1, acc);
            f32x4 bb = *(const f32x4*)&bd1[16 * t + 4 * g];
            f32x4 aa = *(const f32x4*)&ad[16 * t + 4 * g];
            f32x4 v;
#pragma unroll
            for (int r = 0; r < 4; ++r) { float q = acc[r] + bb[r]; v[r] = q >= 0.f ? q : aa[r] * q; }
            awr(1, t, v);
        }
    }

    // ---------------- P2: rec = x + h@Wd2 + bd2 -> buf0 ----------------
    {
        f32x4 xr[4];
#pragma unroll
        for (int t = 0; t < 4; ++t)
            xr[t] = *(const f32x4*)&x[(size_t)nglob * 64 + 16 * t + 4 * g];
        short8 ah0 = afr(1, 0, wv, 0), ah1 = afr(1, 0, wv, 1);
        short8 al0 = afr(1, 1, wv, 0), al1 = afr(1, 1, wv, 1);
#pragma unroll
        for (int t = 0; t < 4; ++t) {
            f32x4 acc = {0.f, 0.f, 0.f, 0.f};
            GEMM6(B_D2, 2, t, ah0, ah1, al0, al1, acc);
            f32x4 bb = *(const f32x4*)&bd2[16 * t + 4 * g];
            f32x4 v;
#pragma unroll
            for (int r = 0; r < 4; ++r) v[r] = acc[r] + bb[r] + xr[t][r];
            awr(0, t, v);
        }
    }

    // ---------------- P3: p = prelu(rec@Wp1+bp1) -> buf1 ----------------
    {
        short8 ah0 = afr(0, 0, wv, 0), ah1 = afr(0, 0, wv, 1);
        short8 al0 = afr(0, 1, wv, 0), al1 = afr(0, 1, wv, 1);
#pragma unroll
        for (int t = 0; t < 4; ++t) {
            f32x4 acc = {0.f, 0.f, 0.f, 0.f};
            GEMM6(B_P1, 2, t, ah0, ah1, al0, al1, acc);
            f32x4 bb = *(const f32x4*)&bp1[16 * t + 4 * g];
            f32x4 aa = *(const f32x4*)&ap[16 * t + 4 * g];
            f32x4 v;
#pragma unroll
            for (int r = 0; r < 4; ++r) { float q = acc[r] + bb[r]; v[r] = q >= 0.f ? q : aa[r] * q; }
            awr(1, t, v);
        }
    }
    __syncthreads();   // P4 reads all stripes of buf1

    // ---------------- P4: cur_pred = p@Wp2 + bp2 (wave owns 2 col-tiles, all stripes) ----------------
    {
        short8 W8[8];
#pragma unroll
        for (int q = 0; q < 2; ++q) {
            int ct = 2 * wv + q;
            W8[q * 4 + 0] = wf(B_P2, 2, ct, 0, 0); W8[q * 4 + 1] = wf(B_P2, 2, ct, 1, 0);
            W8[q * 4 + 2] = wf(B_P2, 2, ct, 0, 1); W8[q * 4 + 3] = wf(B_P2, 2, ct, 1, 1);
        }
        for (int st = 0; st < 8; ++st) {
            short8 ah0 = afr(1, 0, st, 0), ah1 = afr(1, 0, st, 1);
            short8 al0 = afr(1, 1, st, 0), al1 = afr(1, 1, st, 1);
            int ng = n0 + st * 16 + ln;
#pragma unroll
            for (int q = 0; q < 2; ++q) {
                int ct = 2 * wv + q;
                f32x4 acc = {0.f, 0.f, 0.f, 0.f};
                acc = MFMA(W8[q * 4 + 0], ah0, acc); acc = MFMA(W8[q * 4 + 1], ah1, acc);
                acc = MFMA(W8[q * 4 + 0], al0, acc); acc = MFMA(W8[q * 4 + 1], al1, acc);
                acc = MFMA(W8[q * 4 + 2], ah0, acc); acc = MFMA(W8[q * 4 + 3], ah1, acc);
                int c0 = ct * 16 + 4 * g;
                size_t ro = (size_t)ng * 255 + c0;
                if (c0 + 3 < 255) {
                    f32x4 bb = *(const f32x4*)&bp2[c0];
                    f32x4 v;
#pragma unroll
                    for (int r = 0; r < 4; ++r) v[r] = acc[r] + bb[r];
                    *(f32x4u*)&outP[ro] = v;
                } else {
#pragma unroll
                    for (int r = 0; r < 3; ++r) outP[ro + r] = acc[r] + bp2[c0 + r];
                }
            }
        }
    }
    __syncthreads();   // P5 overwrites buf1

    // ---------------- P5: u = prelu([rec|bits]@Wu1+bu1) -> buf1, save u in regs ----------------
    f32x4 ures[4];
    {
        short8 ah0 = afr(0, 0, wv, 0), ah1 = afr(0, 0, wv, 1);
        short8 al0 = afr(0, 1, wv, 0), al1 = afr(0, 1, wv, 1);
        int mk = maskI[nloc];
        short8 bits;
#pragma unroll
        for (int i = 0; i < 8; ++i)
            bits[i] = (short)((g == 0 && ((mk >> i) & 1)) ? 0x4380 : 0);
#pragma unroll
        for (int t = 0; t < 4; ++t) {
            f32x4 acc = {0.f, 0.f, 0.f, 0.f};
            GEMM6(B_U1, 3, t, ah0, ah1, al0, al1, acc);
            short8 wh2 = wf(B_U1, 3, t, 2, 0), wl2 = wf(B_U1, 3, t, 2, 1);
            acc = MFMA(wh2, bits, acc); acc = MFMA(wl2, bits, acc);
            f32x4 bb = *(const f32x4*)&bu1[16 * t + 4 * g];
            f32x4 aa = *(const f32x4*)&au1[16 * t + 4 * g];
            f32x4 v;
#pragma unroll
            for (int r = 0; r < 4; ++r) { float q = acc[r] + bb[r]; v[r] = q >= 0.f ? q : aa[r] * q; }
            ures[t] = v;
            awr(1, t, v);
        }
    }

    // ---------------- P6: h2 = prelu(u@Wu2+bu2) -> buf0 ----------------
    {
        short8 ah0 = afr(1, 0, wv, 0), ah1 = afr(1, 0, wv, 1);
        short8 al0 = afr(1, 1, wv, 0), al1 = afr(1, 1, wv, 1);
#pragma unroll
        for (int t = 0; t < 4; ++t) {
            f32x4 acc = {0.f, 0.f, 0.f, 0.f};
            GEMM6(B_U2, 2, t, ah0, ah1, al0, al1, acc);
            f32x4 bb = *(const f32x4*)&bu2[16 * t + 4 * g];
            f32x4 aa = *(const f32x4*)&au2[16 * t + 4 * g];
            f32x4 v;
#pragma unroll
            for (int r = 0; r < 4; ++r) { float q = acc[r] + bb[r]; v[r] = q >= 0.f ? q : aa[r] * q; }
            awr(0, t, v);
        }
    }

    // ---------------- P7: u_new = u + h2@Wu3 + bu3 -> buf1 ----------------
    {
        short8 ah0 = afr(0, 0, wv, 0), ah1 = afr(0, 0, wv, 1);
        short8 al0 = afr(0, 1, wv, 0), al1 = afr(0, 1, wv, 1);
#pragma unroll
        for (int t = 0; t < 4; ++t) {
            f32x4 acc = {0.f, 0.f, 0.f, 0.f};
            GEMM6(B_U3, 2, t, ah0, ah1, al0, al1, acc);
            f32x4 bb = *(const f32x4*)&bu3[16 * t + 4 * g];
            f32x4 v;
#pragma unroll
            for (int r = 0; r < 4; ++r) v[r] = acc[r] + bb[r] + ures[t][r];
            awr(1, t, v);
        }
    }
    __syncthreads();   // P8 reads all stripes of buf1

    // ---------------- P8: up = u@Wu4 + bu4; wave wv == child wv; masked scatter ----------------
    {
        short8 W16[16];
#pragma unroll
        for (int t = 0; t < 4; ++t) {
            int ct = 4 * wv + t;
            W16[t * 4 + 0] = wf(B_U4, 2, ct, 0, 0); W16[t * 4 + 1] = wf(B_U4, 2, ct, 1, 0);
            W16[t * 4 + 2] = wf(B_U4, 2, ct, 0, 1); W16[t * 4 + 3] = wf(B_U4, 2, ct, 1, 1);
        }
        for (int st = 0; st < 8; ++st) {
            short8 ah0 = afr(1, 0, st, 0), ah1 = afr(1, 0, st, 1);
            short8 al0 = afr(1, 1, st, 0), al1 = afr(1, 1, st, 1);
            int nl = st * 16 + ln;
            int mk = maskI[nl];
            bool wr = (mk >> wv) & 1;
            int d = baseI[nl] + __popc(mk & ((1 << wv) - 1));
#pragma unroll
            for (int t = 0; t < 4; ++t) {
                int ct = 4 * wv + t;
                f32x4 acc = {0.f, 0.f, 0.f, 0.f};
                acc = MFMA(W16[t * 4 + 0], ah0, acc); acc = MFMA(W16[t * 4 + 1], ah1, acc);
                acc = MFMA(W16[t * 4 + 0], al0, acc); acc = MFMA(W16[t * 4 + 1], al1, acc);
                acc = MFMA(W16[t * 4 + 2], ah0, acc); acc = MFMA(W16[t * 4 + 3], ah1, acc);
                if (wr) {
                    f32x4 bb = *(const f32x4*)&bu4[ct * 16 + 4 * g];
                    f32x4 v;
#pragma unroll
                    for (int r = 0; r < 4; ++r) v[r] = acc[r] + bb[r];
                    *(f32x4*)&outF[(size_t)d * 64 + 16 * t + 4 * g] = v;
                }
            }
        }
    }
#undef GEMM6
}

extern "C" void kernel_launch(void* const* d_in, const int* in_sizes, int n_in,
                              void* d_out, int out_size, void* d_ws, size_t ws_size,
                              hipStream_t stream) {
    const float* x   = (const float*)d_in[0];
    const int*   bin = (const int*)d_in[1];
    const int*   sel = (const int*)d_in[2];
    const int    M   = in_sizes[2];
    const float *Wd1 = (const float*)d_in[3],  *bd1 = (const float*)d_in[4],  *ad  = (const float*)d_in[5];
    const float *Wd2 = (const float*)d_in[6],  *bd2 = (const float*)d_in[7];
    const float *Wp1 = (const float*)d_in[8],  *bp1 = (const float*)d_in[9],  *ap  = (const float*)d_in[10];
    const float *Wp2 = (const float*)d_in[11], *bp2 = (const float*)d_in[12];
    const float *Wu1 = (const float*)d_in[13], *bu1 = (const float*)d_in[14], *au1 = (const float*)d_in[15];
    const float *Wu2 = (const float*)d_in[16], *bu2 = (const float*)d_in[17], *au2 = (const float*)d_in[18];
    const float *Wu3 = (const float*)d_in[19], *bu3 = (const float*)d_in[20];
    const float *Wu4 = (const float*)d_in[21], *bu4 = (const float*)d_in[22];

    float* out  = (float*)d_out;
    float* outF = out;
    float* outP = out + (size_t)M * 64;
    float* outO = outP + (size_t)NPTS * 255;

    short* ws = (short*)d_ws;
    prep_weights<<<296, 256, 0, stream>>>(Wd1, Wd2, Wp1, Wp2, Wu1, Wu2, Wu3, Wu4, ws);
    fused_main<<<NBLK, NTH, 0, stream>>>(x, bin, sel, M,
                                         bd1, ad, bd2, bp1, ap, bp2,
                                         bu1, au1, bu2, au2, bu3, bu4,
                                         ws, outF, outP, outO);
}